// Round 2
// baseline (1760.046 us; speedup 1.0000x reference)
//
#include <hip/hip_runtime.h>

using ushort = unsigned short;
using bf16x8  = __attribute__((ext_vector_type(8))) __bf16;
using ushort8 = __attribute__((ext_vector_type(8))) unsigned short;
using f32x4   = __attribute__((ext_vector_type(4))) float;

__device__ __forceinline__ float bf2f(ushort u) {
    union { unsigned int i; float f; } v; v.i = ((unsigned int)u) << 16; return v.f;
}
__device__ __forceinline__ ushort f2bf(float f) {
    union { float f; unsigned int i; } v; v.f = f;
    unsigned int r = v.i + 0x7FFFu + ((v.i >> 16) & 1u);
    return (ushort)(r >> 16);
}
__device__ __forceinline__ bf16x8 ld8(const ushort* p) {
    return __builtin_bit_cast(bf16x8, *(const ushort8*)p);
}
// load 8 consecutive elements at element-index e, as bf16x8, from bf16 or f32 storage
template<bool F32>
__device__ __forceinline__ bf16x8 ld8e(const void* p, size_t e) {
    if constexpr (F32) {
        const float* q = (const float*)p + e;
        bf16x8 r;
#pragma unroll
        for (int j = 0; j < 8; ++j) r[j] = (__bf16)q[j];
        return r;
    } else {
        return ld8((const ushort*)p + e);
    }
}
template<bool F32>
__device__ __forceinline__ float ld1e(const void* p, size_t e) {
    if constexpr (F32) return ((const float*)p)[e];
    else return bf2f(((const ushort*)p)[e]);
}

// ---------------------------------------------------------------------------
// Dtype sniffer: decides bf16 (flag=0) vs f32 (flag=1) storage from `query`.
// bf16 data: every halfword is a real ~N(0,1) value -> max |.| small.
// f32 data: even halfwords are mantissa bits -> random exponents -> huge max.
// ---------------------------------------------------------------------------
__global__ void sniff_kernel(const ushort* __restrict__ q, int* __restrict__ flag) {
    const int lane = threadIdx.x;              // 64 threads, 1 block
    float mx = 0.0f;
    for (int i = lane; i < 512; i += 64) {
        float v = bf2f(q[2 * i]);              // even halfword
        mx = fmaxf(mx, fabsf(v));
    }
#pragma unroll
    for (int off = 32; off >= 1; off >>= 1) mx = fmaxf(mx, __shfl_xor(mx, off, 64));
    if (lane == 0) *flag = (mx > 1.0e6f) ? 1 : 0;
}

// ---------------------------------------------------------------------------
// C[M=8192, N=1024] = A[M, K=1024] * W[N, K]^T + bias, epilogue variants:
// EPI 0: none   EPI 1: RoPE (N-tile == one head of 64)   EPI 2: sigmoid
// block = 256 threads (4 waves), tile 64x64; wave w: rows w*16..+15, all 64 cols.
// AF32/WF32: storage dtype of A / W+bias+rope. OF32: output store dtype.
// EXPECT: runs only when *flag == EXPECT (dual-variant dispatch).
// ---------------------------------------------------------------------------
template<int EPI, bool AF32, bool WF32, bool OF32, int EXPECT>
__global__ __launch_bounds__(256) void gemm_bt(
    const void* __restrict__ A, const void* __restrict__ W,
    const void* __restrict__ bias,
    const void* __restrict__ rc, const void* __restrict__ rs,
    void* __restrict__ C, const int* __restrict__ flag)
{
    if (*flag != EXPECT) return;
    constexpr int Kd = 1024, Nd = 1024;
    const int nb   = blockIdx.x & 15;   // N/64 = 16
    const int mb   = blockIdx.x >> 4;   // M/64 = 128
    const int wave = threadIdx.x >> 6;
    const int lane = threadIdx.x & 63;
    const int quad = lane >> 4;
    const int l16  = lane & 15;

    const size_t aoff = (size_t)(mb*64 + wave*16 + l16) * Kd + quad*8;
    const size_t woff = (size_t)(nb*64 + l16) * Kd + quad*8;

    f32x4 acc[4] = {};
    for (int k0 = 0; k0 < Kd; k0 += 32) {
        bf16x8 a = ld8e<AF32>(A, aoff + k0);
#pragma unroll
        for (int t = 0; t < 4; ++t) {
            bf16x8 b = ld8e<WF32>(W, woff + (size_t)t*16*Kd + k0);
            acc[t] = __builtin_amdgcn_mfma_f32_16x16x32_bf16(a, b, acc[t], 0, 0, 0);
        }
    }

    const int rowg0 = mb*64 + wave*16 + quad*4;
#pragma unroll
    for (int r = 0; r < 4; ++r) {
        const int rowg = rowg0 + r;            // == b*1024 + l  (Lq == Lk == 1024)
        float v[4];
#pragma unroll
        for (int t = 0; t < 4; ++t) v[t] = acc[t][r] + ld1e<WF32>(bias, nb*64 + t*16 + l16);
        if (EPI == 1) {
#pragma unroll
            for (int t = 0; t < 2; ++t) {      // pair col j with j+32 (same head)
                const size_t ci = (size_t)rowg*64 + t*16 + l16;
                const float c = ld1e<AF32>(rc, ci), s = ld1e<AF32>(rs, ci);
                const float x1 = v[t], x2 = v[t+2];
                v[t]   = x1*c - x2*s;
                v[t+2] = x2*c + x1*s;
            }
        } else if (EPI == 2) {
#pragma unroll
            for (int t = 0; t < 4; ++t) v[t] = 1.0f/(1.0f + __expf(-v[t]));
        }
#pragma unroll
        for (int t = 0; t < 4; ++t) {
            const size_t idx = (size_t)rowg*Nd + nb*64 + t*16 + l16;
            if constexpr (OF32) ((float*)C)[idx] = v[t];
            else                ((ushort*)C)[idx] = f2bf(v[t]);
        }
    }
}

// ---------------------------------------------------------------------------
// Flash attention: 1 wave per (b, h, 16-row q-tile). 32-key blocks,
// online softmax, P->A-layout via LDS, V staged in LDS. Gate fused in epilogue.
// Only touches bf16 workspace -> dtype-mode independent.
// ---------------------------------------------------------------------------
__global__ __launch_bounds__(64) void attn_kernel(
    const ushort* __restrict__ Qp, const ushort* __restrict__ Kp,
    const ushort* __restrict__ Vp, const ushort* __restrict__ G,
    const unsigned char* __restrict__ mask, ushort* __restrict__ O)
{
    const int qt = blockIdx.x & 63;          // Lq/16
    const int h  = (blockIdx.x >> 6) & 15;
    const int b  = blockIdx.x >> 10;
    const int lane = threadIdx.x;
    const int quad = lane >> 4;
    const int l16  = lane & 15;
    const size_t Dm = 1024;

    __shared__ __align__(16) ushort ldsP[16*32];
    __shared__ __align__(16) ushort ldsV[32*64];

    const ushort* Qb = Qp + ((size_t)b*1024 + (size_t)qt*16 + l16)*Dm + h*64 + quad*8;
    const bf16x8 qa0 = ld8(Qb);
    const bf16x8 qa1 = ld8(Qb + 32);

    float m_r[4], l_r[4];
    f32x4 o[4] = {};
#pragma unroll
    for (int r = 0; r < 4; ++r) { m_r[r] = -3.0e38f; l_r[r] = 0.0f; }

    const float scale = 0.125f;   // 1/sqrt(64)
    for (int k0 = 0; k0 < 1024; k0 += 32) {
        // stage V block (32 keys x 64 hd) into LDS
        const ushort* Vb = Vp + ((size_t)b*1024 + k0)*Dm + h*64;
#pragma unroll
        for (int c2 = 0; c2 < 4; ++c2) {
            const int idx = c2*512 + lane*8;
            const int vr = idx >> 6, vc = idx & 63;
            *(ushort8*)&ldsV[idx] = *(const ushort8*)(Vb + (size_t)vr*Dm + vc);
        }
        // S = Q K^T  (two 16-col tiles)
        f32x4 s[2] = {};
#pragma unroll
        for (int ct = 0; ct < 2; ++ct) {
            const ushort* Kb = Kp + ((size_t)b*1024 + k0 + ct*16 + l16)*Dm + h*64 + quad*8;
            s[ct] = __builtin_amdgcn_mfma_f32_16x16x32_bf16(qa0, ld8(Kb),      s[ct], 0,0,0);
            s[ct] = __builtin_amdgcn_mfma_f32_16x16x32_bf16(qa1, ld8(Kb + 32), s[ct], 0,0,0);
        }
        const bool msk0 = mask[(size_t)b*1024 + k0 + l16] != 0;
        const bool msk1 = mask[(size_t)b*1024 + k0 + 16 + l16] != 0;
        __syncthreads();
        // online softmax per q-row (row = quad*4 + r; 16 cols live in the quad's lanes)
#pragma unroll
        for (int r = 0; r < 4; ++r) {
            float s0 = msk0 ? -1e30f : s[0][r]*scale;
            float s1 = msk1 ? -1e30f : s[1][r]*scale;
            float mx = fmaxf(s0, s1);
#pragma unroll
            for (int off = 8; off >= 1; off >>= 1) mx = fmaxf(mx, __shfl_xor(mx, off, 16));
            const float mnew  = fmaxf(m_r[r], mx);
            const float alpha = __expf(m_r[r] - mnew);
            const float p0 = __expf(s0 - mnew), p1 = __expf(s1 - mnew);
            float ps = p0 + p1;
#pragma unroll
            for (int off = 8; off >= 1; off >>= 1) ps += __shfl_xor(ps, off, 16);
            l_r[r] = l_r[r]*alpha + ps;
            m_r[r] = mnew;
#pragma unroll
            for (int t = 0; t < 4; ++t) o[t][r] *= alpha;
            ldsP[(quad*4 + r)*32 + l16]      = f2bf(p0);
            ldsP[(quad*4 + r)*32 + 16 + l16] = f2bf(p1);
        }
        __syncthreads();
        // O += P V : P re-read in A-layout, V gathered column-wise from LDS
        const bf16x8 pa = __builtin_bit_cast(bf16x8, *(const ushort8*)&ldsP[l16*32 + quad*8]);
#pragma unroll
        for (int t = 0; t < 4; ++t) {
            ushort8 tmp;
#pragma unroll
            for (int j = 0; j < 8; ++j) tmp[j] = ldsV[(quad*8 + j)*64 + t*16 + l16];
            o[t] = __builtin_amdgcn_mfma_f32_16x16x32_bf16(pa, __builtin_bit_cast(bf16x8, tmp), o[t], 0,0,0);
        }
        __syncthreads();
    }
    // epilogue: normalize, gate, store bf16
    const int rowg0 = b*1024 + qt*16 + quad*4;
#pragma unroll
    for (int r = 0; r < 4; ++r) {
        const float inv = 1.0f / l_r[r];
#pragma unroll
        for (int t = 0; t < 4; ++t) {
            const size_t idx = (size_t)(rowg0 + r)*Dm + h*64 + t*16 + l16;
            O[idx] = f2bf(o[t][r] * inv * bf2f(G[idx]));
        }
    }
}

extern "C" void kernel_launch(void* const* d_in, const int* in_sizes, int n_in,
                              void* d_out, int out_size, void* d_ws, size_t ws_size,
                              hipStream_t stream)
{
    const void* query = d_in[0];
    const void* key   = d_in[1];
    const void* value = d_in[2];
    const void* Wq    = d_in[3];
    const void* bq    = d_in[4];
    const void* Wk    = d_in[5];
    const void* bk    = d_in[6];
    const void* Wv    = d_in[7];
    const void* bv    = d_in[8];
    const void* Wg    = d_in[9];
    const void* bg    = d_in[10];
    const void* Wo    = d_in[11];
    const void* bo    = d_in[12];
    const void* rc    = d_in[13];
    const void* rs    = d_in[14];
    const unsigned char* mask = (const unsigned char*)d_in[15];

    char* ws = (char*)d_ws;
    const size_t MB16 = (size_t)16 << 20;        // 8192*1024*2 bytes
    ushort* Qp = (ushort*)(ws);
    ushort* Kp = (ushort*)(ws + 1*MB16);
    ushort* Vp = (ushort*)(ws + 2*MB16);
    ushort* Gt = (ushort*)(ws + 3*MB16);
    ushort* Ag = (ushort*)(ws + 4*MB16);
    int*  flag = (int*)(ws + 5*MB16);

    const dim3 gb(2048), gt(256);
    hipLaunchKernelGGL(sniff_kernel, dim3(1), dim3(64), 0, stream, (const ushort*)query, flag);

    // bf16-mode variants (flag==0)
    hipLaunchKernelGGL((gemm_bt<1,false,false,false,0>), gb, gt, 0, stream, query, Wq, bq, rc, rs, Qp, flag);
    hipLaunchKernelGGL((gemm_bt<1,false,false,false,0>), gb, gt, 0, stream, key,   Wk, bk, rc, rs, Kp, flag);
    hipLaunchKernelGGL((gemm_bt<0,false,false,false,0>), gb, gt, 0, stream, value, Wv, bv, rc, rs, Vp, flag);
    hipLaunchKernelGGL((gemm_bt<2,false,false,false,0>), gb, gt, 0, stream, query, Wg, bg, rc, rs, Gt, flag);
    // f32-mode variants (flag==1)
    hipLaunchKernelGGL((gemm_bt<1,true,true,false,1>), gb, gt, 0, stream, query, Wq, bq, rc, rs, Qp, flag);
    hipLaunchKernelGGL((gemm_bt<1,true,true,false,1>), gb, gt, 0, stream, key,   Wk, bk, rc, rs, Kp, flag);
    hipLaunchKernelGGL((gemm_bt<0,true,true,false,1>), gb, gt, 0, stream, value, Wv, bv, rc, rs, Vp, flag);
    hipLaunchKernelGGL((gemm_bt<2,true,true,false,1>), gb, gt, 0, stream, query, Wg, bg, rc, rs, Gt, flag);

    hipLaunchKernelGGL(attn_kernel, dim3(8192), dim3(64), 0, stream, Qp, Kp, Vp, Gt, mask, Ag);

    // final projection: A (=Ag) is always bf16 workspace; W/bias + output follow mode
    hipLaunchKernelGGL((gemm_bt<0,false,false,false,0>), gb, gt, 0, stream, Ag, Wo, bo, rc, rs, d_out, flag);
    hipLaunchKernelGGL((gemm_bt<0,false,true, true, 1>), gb, gt, 0, stream, Ag, Wo, bo, rc, rs, d_out, flag);
}